// Round 8
// baseline (28.199 us; speedup 1.0000x reference)
//
#include <hip/hip_runtime.h>

#define FD 768
#define HD 256
#define NF 512
#define NC 512
#define PAIRS (NF * (NF - 1) / 2)   // 130816

typedef __attribute__((ext_vector_type(4))) float f32x4;
typedef __attribute__((ext_vector_type(8))) short bf16x8;

// RNE float->bf16, packed pair (a = low 16, b = high 16)
__device__ inline unsigned bf16pk(float a, float b) {
    unsigned ua = __float_as_uint(a), ub = __float_as_uint(b);
    ua = (ua + 0x7FFFu + ((ua >> 16) & 1u)) >> 16;
    ub = (ub + 0x7FFFu + ((ub >> 16) & 1u)) >> 16;
    return ua | (ub << 16);
}

// ---------------------------------------------------------------------------
// Kernel 0 (prep): Ebf[r][k] = bf16(E[r][k])  (linear convert, 384 blocks)
//                  Wt[c][k]  = bf16(W1[k + (c<256?0:768)][c&255]) (192 blocks)
// Both outputs are k-contiguous bf16 — exactly the MFMA fragment layout —
// so the GEMM kernel needs no LDS and no transpose.
// ---------------------------------------------------------------------------
__global__ __launch_bounds__(256) void prep_kernel(
    const float* __restrict__ E, const float* __restrict__ W1,
    ushort* __restrict__ Ebf, ushort* __restrict__ Wt)
{
    const int bid = blockIdx.x, tid = threadIdx.x;
    if (bid < 384) {
        // E convert: 98304 f4 tasks, coalesced read + 8B write
        int idx = bid * 256 + tid;
        float4 v = ((const float4*)E)[idx];
        uint2 pk;
        pk.x = bf16pk(v.x, v.y);
        pk.y = bf16pk(v.z, v.w);
        *(uint2*)(Ebf + (size_t)idx * 4) = pk;
    } else {
        // W transpose: 49152 tasks = (c-quad q, k-pair kp)
        int t = (bid - 384) * 256 + tid;
        int q = t & 127, kp = t >> 7;          // c = 4q..4q+3, k = 2kp,2kp+1
        int off = (q < 64) ? 0 : FD;
        int cq = q & 63;
        const float4* W14 = (const float4*)W1;  // row pitch 64 f4
        float4 w0 = W14[(size_t)(2 * kp + off) * 64 + cq];
        float4 w1 = W14[(size_t)(2 * kp + 1 + off) * 64 + cq];
        *(unsigned*)(Wt + (size_t)(4 * q + 0) * FD + 2 * kp) = bf16pk(w0.x, w1.x);
        *(unsigned*)(Wt + (size_t)(4 * q + 1) * FD + 2 * kp) = bf16pk(w0.y, w1.y);
        *(unsigned*)(Wt + (size_t)(4 * q + 2) * FD + 2 * kp) = bf16pk(w0.z, w1.z);
        *(unsigned*)(Wt + (size_t)(4 * q + 3) * FD + 2 * kp) = bf16pk(w0.w, w1.w);
    }
}

// ---------------------------------------------------------------------------
// Kernel 1: C = E @ [W1top|W1bot] + [b1|0] via bf16 MFMA — NO LDS, no barrier.
// Grid 16x16, 256 thr = 4 waves (2x2 of 16x16 tiles), K=768 = 24 mfma steps.
// Each fragment = one contiguous global dwordx4 from L2-resident bf16:
//   A (m = C-col): Wt[c0+16wc+(l&15)][32ks + 8(l>>4) + 0..7]
//   B (n = C-row): Ebf[r0+16wr+(l&15)][same k]
// D layout (R7-validated): lane l, reg p -> C[r0+16wr+(l&15)][c0+16wc+4(l>>4)+p]
// ---------------------------------------------------------------------------
__global__ __launch_bounds__(256) void gemm_mfma_kernel(
    const ushort* __restrict__ Ebf, const ushort* __restrict__ Wt,
    const float* __restrict__ b1, float* __restrict__ C)
{
    const int tid  = threadIdx.x;
    const int lane = tid & 63, wave = tid >> 6;
    const int wr = wave >> 1, wc = wave & 1;
    const int r0 = blockIdx.y * 32, c0 = blockIdx.x * 32;
    const int n = lane & 15, g = lane >> 4;

    const ushort* aptr = Wt  + (size_t)(c0 + 16 * wc + n) * FD + 8 * g;
    const ushort* bptr = Ebf + (size_t)(r0 + 16 * wr + n) * FD + 8 * g;

    f32x4 acc = {0.f, 0.f, 0.f, 0.f};
    #pragma unroll 8
    for (int ks = 0; ks < 24; ++ks) {
        bf16x8 af = *(const bf16x8*)(aptr + 32 * ks);
        bf16x8 bf = *(const bf16x8*)(bptr + 32 * ks);
        acc = __builtin_amdgcn_mfma_f32_16x16x32_bf16(af, bf, acc, 0, 0, 0);
    }

    const int row = r0 + 16 * wr + n;
    const int col = c0 + 16 * wc + 4 * g;
    float4 b = {0.f, 0.f, 0.f, 0.f};
    if (c0 < 256) b = ((const float4*)b1)[col >> 2];
    float4 o = {acc[0] + b.x, acc[1] + b.y, acc[2] + b.z, acc[3] + b.w};
    *(float4*)&C[(size_t)row * NC + col] = o;
}

// ---------------------------------------------------------------------------
// Kernel 2: pair scores (unchanged from R7 — validated). 16x32 tile, 272
// blocks, 1x2 micro. LDS f4 with XOR swizzle; W2 via uniform global load.
// ---------------------------------------------------------------------------
__global__ __launch_bounds__(256) void pair_kernel(
    const float* __restrict__ C, const float* __restrict__ W2,
    const float* __restrict__ b2, float* __restrict__ out)
{
    __shared__ float4 As[16 * 64];
    __shared__ float4 Bs[32 * 64];

    int rem = blockIdx.x, bi = 0;
    while (rem >= 16 - (bi >> 1)) { rem -= 16 - (bi >> 1); ++bi; }
    const int bj = (bi >> 1) + rem;
    const int i0 = bi * 16, j0 = bj * 32;

    const int tid = threadIdx.x;
    const float4* C4 = (const float4*)C;        // row pitch 128 f4

    #pragma unroll
    for (int s = 0; s < 4; ++s) {               // A: 16 rows x 64 f4
        int idx = tid + 256 * s;
        int row = idx >> 6, c4 = idx & 63;
        As[row * 64 + (c4 ^ ((row >> 1) & 7))] = C4[(i0 + row) * 128 + c4];
    }
    #pragma unroll
    for (int s = 0; s < 8; ++s) {               // B: 32 rows x 64 f4
        int idx = tid + 256 * s;
        int row = idx >> 6, c4 = idx & 63;
        Bs[row * 64 + (c4 ^ ((row >> 1) & 7))] = C4[(j0 + row) * 128 + 64 + c4];
    }
    __syncthreads();

    const int tx = tid & 15, ty = tid >> 4;
    const int keyA = (ty >> 1) & 7, keyB = tx & 7;
    const float4* W24 = (const float4*)W2;

    float acc0 = 0.f, acc1 = 0.f;
    #pragma unroll 8
    for (int k4 = 0; k4 < HD / 4; ++k4) {
        float4 a   = As[ty * 64 + (k4 ^ keyA)];
        float4 b0  = Bs[(2 * tx + 0) * 64 + (k4 ^ keyB)];
        float4 b1v = Bs[(2 * tx + 1) * 64 + (k4 ^ keyB)];
        float4 w = W24[k4];                     // uniform -> s_load
        acc0 = fmaf(fmaxf(a.x + b0.x, 0.f), w.x, acc0);
        acc0 = fmaf(fmaxf(a.y + b0.y, 0.f), w.y, acc0);
        acc0 = fmaf(fmaxf(a.z + b0.z, 0.f), w.z, acc0);
        acc0 = fmaf(fmaxf(a.w + b0.w, 0.f), w.w, acc0);
        acc1 = fmaf(fmaxf(a.x + b1v.x, 0.f), w.x, acc1);
        acc1 = fmaf(fmaxf(a.y + b1v.y, 0.f), w.y, acc1);
        acc1 = fmaf(fmaxf(a.z + b1v.z, 0.f), w.z, acc1);
        acc1 = fmaf(fmaxf(a.w + b1v.w, 0.f), w.w, acc1);
    }

    const float bias2 = b2[0];
    const int i = i0 + ty;
    #pragma unroll
    for (int u = 0; u < 2; ++u) {
        int j = j0 + 2 * tx + u;
        float v = u ? acc1 : acc0;
        if (j > i) {
            int p = i * (2 * NF - i - 1) / 2 + (j - i - 1);
            out[p]             = (float)i;
            out[PAIRS + p]     = (float)j;
            out[2 * PAIRS + p] = v + bias2;
        }
    }
}

extern "C" void kernel_launch(void* const* d_in, const int* in_sizes, int n_in,
                              void* d_out, int out_size, void* d_ws, size_t ws_size,
                              hipStream_t stream) {
    const float* E  = (const float*)d_in[0];
    const float* W1 = (const float*)d_in[1];
    const float* b1 = (const float*)d_in[2];
    const float* W2 = (const float*)d_in[3];
    const float* b2 = (const float*)d_in[4];
    float* out = (float*)d_out;

    ushort* Ebf = (ushort*)d_ws;                       // 512*768 bf16 (768 KB)
    ushort* Wt  = Ebf + (size_t)NF * FD;               // 512*768 bf16 (768 KB)
    float*  C   = (float*)((char*)d_ws + 2 * (size_t)NF * FD * 2);  // 1 MiB

    prep_kernel<<<576, 256, 0, stream>>>(E, W1, Ebf, Wt);
    gemm_mfma_kernel<<<dim3(16, 16), 256, 0, stream>>>(Ebf, Wt, b1, C);
    pair_kernel<<<272, 256, 0, stream>>>(C, W2, b2, out);
}